// Round 15
// baseline (1009.515 us; speedup 1.0000x reference)
//
#include <hip/hip_runtime.h>
#include <hip/hip_bf16.h>
#include <cstddef>
#include <cstdint>

typedef __hip_bfloat16 bf16;
typedef __attribute__((ext_vector_type(8))) short short8;      // 8 bf16 (4 VGPRs)
typedef __attribute__((ext_vector_type(4))) float floatx4;     // MFMA acc

static __device__ __forceinline__ float b2f(bf16 v) { return __bfloat162float(v); }

static __device__ __forceinline__ short f2bf(float f) {
    unsigned u = __float_as_uint(f);
    unsigned r = u + 0x7FFF + ((u >> 16) & 1);
    return (short)(r >> 16);
}
static __device__ __forceinline__ float bf2f(short h) {
    return __uint_as_float(((unsigned)(unsigned short)h) << 16);
}
// mode: 0=zero, 1=bf16-stored, 2=fp32-stored
static __device__ __forceinline__ float loadf(const void* p, int mode, size_t i) {
    if (mode == 1) return b2f(((const bf16*)p)[i]);
    if (mode == 2) return ((const float*)p)[i];
    return 0.f;
}

#define NCONV 35
#define NREP 16
struct DetArgs { const void* src[NCONV]; int n[NCONV]; };

// ---------------- dtype detection (one block per buffer) ----------------
__global__ void detect_all(DetArgs a, int* __restrict__ modes) {
    int b = blockIdx.x;
    int n = a.n[b];
    const unsigned short* w = (const unsigned short*)a.src[b];
    __shared__ int cz, cbad, cevz, codz;
    if (threadIdx.x == 0) { cz = 0; cbad = 0; cevz = 0; codz = 0; }
    __syncthreads();
    int K = n < 2048 ? n : 2048;
    int z = 0, bad = 0, evz = 0, odz = 0;
    for (int i = threadIdx.x; i < K; i += blockDim.x) {
        unsigned short v = w[i];
        int e = (v >> 7) & 0xFF;
        bool isz = (v & 0x7FFF) == 0;
        if (isz) { z++; if (i & 1) odz++; else evz++; }
        else if (e < 91 || e > 140) bad++;
    }
    atomicAdd(&cz, z); atomicAdd(&cbad, bad);
    atomicAdd(&cevz, evz); atomicAdd(&codz, odz);
    __syncthreads();
    if (threadIdx.x == 0) {
        int mode;
        if (cz >= K) mode = 0;
        else if (cbad * 16 > K) mode = 2;
        else if (cevz * 4 > K && codz * 16 < K) mode = 2;
        else mode = 1;
        modes[b] = mode;
    }
}

// ---------------- batched weight transpose -> bf16 Wt[n][Kpad] ----------------
struct WtArgs {
    const void* W[8]; short* wt[8];
    int midx[8]; int KW[8]; int ldw[8]; int Kpad[8]; int N[8];
};
__global__ void wt_build_all(WtArgs a, const int* __restrict__ modes) {
    int e = blockIdx.y;
    int n = blockIdx.x; if (n >= a.N[e]) return;
    int k = threadIdx.x; if (k >= a.Kpad[e]) return;
    float v = (k < a.KW[e]) ? loadf(a.W[e], modes[a.midx[e]], (size_t)k * a.ldw[e] + n) : 0.f;
    a.wt[e][(size_t)n * a.Kpad[e] + k] = f2bf(v);
}

// ---------------- feature build -> bf16 plane ----------------
__global__ void build_feat_bf16(const void* __restrict__ emb, const int* __restrict__ ids,
                                const void* __restrict__ feats, const int* __restrict__ modes,
                                int eidx, int fidx, unsigned short* __restrict__ P,
                                int nf, int Ws) {
    int i = blockIdx.x;
    int d = threadIdx.x;          // 128
    if (d >= Ws) return;
    float v;
    if (d < 64)           v = loadf(emb, modes[eidx], (size_t)ids[i] * 64 + d);
    else if (d < 64 + nf) v = loadf(feats, modes[fidx], (size_t)i * nf + (d - 64));
    else                  v = 0.f;
    P[(size_t)i * Ws + d] = (unsigned short)f2bf(v);
}

// ---------------- CSR build ----------------
__global__ void csr_count(const int* __restrict__ dst, int nE, int* __restrict__ cnt) {
    int e = blockIdx.x * blockDim.x + threadIdx.x;
    if (e < nE) atomicAdd(&cnt[dst[e]], 1);
}

__global__ __launch_bounds__(256) void scan_part(const int* __restrict__ cnt, int n,
                                                 int* __restrict__ bsum) {
    __shared__ int red[256];
    int blk = blockIdx.x, t = threadIdx.x;
    int base = blk * 1024 + t * 4;
    int s = 0;
    #pragma unroll
    for (int k = 0; k < 4; ++k) { int i = base + k; if (i < n) s += cnt[i]; }
    red[t] = s;
    __syncthreads();
    for (int off = 128; off > 0; off >>= 1) {
        if (t < off) red[t] += red[t + off];
        __syncthreads();
    }
    if (t == 0) bsum[blk] = red[0];
}

__global__ __launch_bounds__(128) void scan_mid(int* __restrict__ bsum, int nb,
                                                int* __restrict__ rowptr, int n) {
    __shared__ int sh[128];
    int t = threadIdx.x;
    int v = (t < nb) ? bsum[t] : 0;
    sh[t] = v;
    __syncthreads();
    for (int off = 1; off < 128; off <<= 1) {
        int u = (t >= off) ? sh[t - off] : 0;
        __syncthreads();
        sh[t] += u;
        __syncthreads();
    }
    if (t < nb) bsum[t] = sh[t] - v;        // exclusive
    if (t == 127) rowptr[n] = sh[127];      // total
}

__global__ __launch_bounds__(256) void scan_fin(const int* __restrict__ cnt, int n,
                                                const int* __restrict__ bsum,
                                                int* __restrict__ rowptr, int* __restrict__ cursor) {
    __shared__ int sh[256];
    int blk = blockIdx.x, t = threadIdx.x;
    int base = blk * 1024 + t * 4;
    int v[4], s = 0;
    #pragma unroll
    for (int k = 0; k < 4; ++k) { int i = base + k; v[k] = (i < n) ? cnt[i] : 0; s += v[k]; }
    sh[t] = s;
    __syncthreads();
    for (int off = 1; off < 256; off <<= 1) {
        int u = (t >= off) ? sh[t - off] : 0;
        __syncthreads();
        sh[t] += u;
        __syncthreads();
    }
    int run = sh[t] - s + bsum[blk];
    #pragma unroll
    for (int k = 0; k < 4; ++k) {
        int i = base + k;
        if (i < n) { rowptr[i] = run; cursor[i] = run; run += v[k]; }
    }
}

__global__ void csr_fill(const int* __restrict__ src, const int* __restrict__ dst,
                         const void* __restrict__ w, const int* __restrict__ modes, int widx,
                         const float* __restrict__ dinv, int nE, int* __restrict__ cursor,
                         int* __restrict__ adj, short* __restrict__ adjw) {
    int e = blockIdx.x * blockDim.x + threadIdx.x;
    if (e < nE) {
        int s = src[e];
        int pos = atomicAdd(&cursor[dst[e]], 1);
        adj[pos] = s;
        if (adjw) adjw[pos] = f2bf(dinv[s] * loadf(w, modes[widx], e));
    }
}

// ---------------- GIN gather, bf16, 16-lane groups, optional fused BN+ReLU ----------------
__global__ __launch_bounds__(256) void gin_gather_bf16(
        const unsigned short* __restrict__ P, const int* __restrict__ rowptr,
        const int* __restrict__ adj, const void* __restrict__ eps,
        const int* __restrict__ modes, int eidx,
        const float* __restrict__ bnsc, const float* __restrict__ bnsh,
        unsigned short* __restrict__ Po, int Ws, int nN) {
    int W8 = Ws >> 3;
    int g = threadIdx.x >> 4;                 // 16 row-groups per block
    int l = threadIdx.x & 15;                 // lane in group
    int i = blockIdx.x * 16 + g;
    if (i >= nN || l >= W8) return;
    float epsv = 1.0f + loadf(eps, modes[eidx], 0);
    float sc[8], sh[8];
    bool bn = bnsc != nullptr;
    if (bn) {
        *(float4*)&sc[0] = *(const float4*)(bnsc + l * 8);
        *(float4*)&sc[4] = *(const float4*)(bnsc + l * 8 + 4);
        *(float4*)&sh[0] = *(const float4*)(bnsh + l * 8);
        *(float4*)&sh[4] = *(const float4*)(bnsh + l * 8 + 4);
    }
    int lo = rowptr[i], hi = rowptr[i + 1];
    float acc[8] = {};
    for (int p = lo; p < hi; ++p) {
        short8 v = *(const short8*)(P + (size_t)adj[p] * Ws + l * 8);
        #pragma unroll
        for (int j = 0; j < 8; ++j) {
            float y = bf2f(v[j]);
            if (bn) y = fmaxf(fmaf(y, sc[j], sh[j]), 0.f);
            acc[j] += y;
        }
    }
    size_t o = (size_t)i * Ws + l * 8;
    short8 sv = *(const short8*)(P + o);
    short8 r;
    #pragma unroll
    for (int j = 0; j < 8; ++j) {
        float y = bf2f(sv[j]);
        if (bn) y = fmaxf(fmaf(y, sc[j], sh[j]), 0.f);
        r[j] = f2bf(acc[j] + epsv * y);
    }
    *(short8*)(Po + o) = r;
}

// ---------------- GCN gather, bf16 input xw, fp32 output ----------------
__global__ __launch_bounds__(256) void gcn_gather_bf16(
        const unsigned short* __restrict__ xw, const int* __restrict__ rowptr,
        const int* __restrict__ adj, const short* __restrict__ adjw,
        const float* __restrict__ dinv, const void* __restrict__ bias,
        const int* __restrict__ modes, int bidx, float* __restrict__ out, int nS) {
    int g = threadIdx.x >> 5;                 // 8 groups
    int l = threadIdx.x & 31;                 // 32 lanes x 8 cols = 256
    int i = blockIdx.x * 8 + g;
    if (i >= nS) return;
    float di = dinv[i];
    int bmode = modes[bidx];
    size_t o = (size_t)i * 256 + l * 8;
    short8 sv = *(const short8*)(xw + o);
    float dd = di * di;
    float acc[8];
    #pragma unroll
    for (int j = 0; j < 8; ++j)
        acc[j] = bf2f(sv[j]) * dd + loadf(bias, bmode, l * 8 + j);
    int lo = rowptr[i], hi = rowptr[i + 1];
    for (int p = lo; p < hi; ++p) {
        float w = di * bf2f(adjw[p]);
        short8 v = *(const short8*)(xw + (size_t)adj[p] * 256 + l * 8);
        #pragma unroll
        for (int j = 0; j < 8; ++j)
            acc[j] += w * bf2f(v[j]);
    }
    *(float4*)(out + o) = *(float4*)&acc[0];
    *(float4*)(out + o + 4) = *(float4*)&acc[4];
}

// ---------------- MFMA GEMM (R14 + software-pipelined K-loop) ------------------------------
// afmt: 0 = bf16, 1 = fp32.  bnsc/bnsh non-null: A' = relu(A*sc+sh).
// omode: 0 = fp32 out (+bias); 1 = bf16 out + replicated column stats; 2 = bf16 out
__global__ __launch_bounds__(256) void gemm_mfma(
        const void* __restrict__ A, int afmt, int ldk,
        const float* __restrict__ bnsc, const float* __restrict__ bnsh,
        const short* __restrict__ Wt,
        const void* __restrict__ bias, const int* __restrict__ modes, int bias_midx,
        float* __restrict__ outF, unsigned short* __restrict__ oB,
        float* __restrict__ statsR, int M, int N, int ksteps, int omode) {
    int tid  = threadIdx.x;
    int wv   = tid >> 6, lane = tid & 63;
    int m16  = lane & 15, q = lane >> 4;
    int bm   = blockIdx.y * 128 + wv * 32;
    int n0   = blockIdx.x * 128;
    int r0 = min(bm + m16, M - 1);
    int r1 = min(bm + 16 + m16, M - 1);
    const short8* ba0 = (const short8*)((const short*)A + (size_t)r0 * ldk + q * 8);
    const short8* ba1 = (const short8*)((const short*)A + (size_t)r1 * ldk + q * 8);
    const float*  fa0 = (const float*)A + (size_t)r0 * ldk + q * 8;
    const float*  fa1 = (const float*)A + (size_t)r1 * ldk + q * 8;
    const short8* pb[8];
    #pragma unroll
    for (int nt = 0; nt < 8; ++nt)
        pb[nt] = (const short8*)(Wt + (size_t)(n0 + nt * 16 + m16) * ldk + q * 8);

    floatx4 acc[2][8];
    #pragma unroll
    for (int mt = 0; mt < 2; ++mt)
        #pragma unroll
        for (int nt = 0; nt < 8; ++nt)
            acc[mt][nt] = (floatx4){0.f, 0.f, 0.f, 0.f};

    bool bn = bnsc != nullptr;

    if (afmt == 0) {
        // software-pipelined: prologue load, issue next iter's loads before compute
        short8 c0 = ba0[0], c1 = ba1[0];
        for (int ks = 0; ks < ksteps; ++ks) {
            short8 n0r, n1r;
            if (ks + 1 < ksteps) {
                n0r = ba0[(ks + 1) * 4];
                n1r = ba1[(ks + 1) * 4];
            }
            short8 a0, a1;
            if (!bn) { a0 = c0; a1 = c1; }
            else {
                int c0i = ks * 32 + q * 8;
                float v0[8], v1[8], scv[8], shv[8];
                #pragma unroll
                for (int j = 0; j < 8; ++j) { v0[j] = bf2f(c0[j]); v1[j] = bf2f(c1[j]); }
                *(float4*)&scv[0] = *(const float4*)(bnsc + c0i);
                *(float4*)&scv[4] = *(const float4*)(bnsc + c0i + 4);
                *(float4*)&shv[0] = *(const float4*)(bnsh + c0i);
                *(float4*)&shv[4] = *(const float4*)(bnsh + c0i + 4);
                #pragma unroll
                for (int j = 0; j < 8; ++j) {
                    a0[j] = f2bf(fmaxf(fmaf(v0[j], scv[j], shv[j]), 0.f));
                    a1[j] = f2bf(fmaxf(fmaf(v1[j], scv[j], shv[j]), 0.f));
                }
            }
            int idx = ks * 4;
            #pragma unroll
            for (int nt = 0; nt < 8; ++nt) {
                short8 b = pb[nt][idx];
                acc[0][nt] = __builtin_amdgcn_mfma_f32_16x16x32_bf16(a0, b, acc[0][nt], 0, 0, 0);
                acc[1][nt] = __builtin_amdgcn_mfma_f32_16x16x32_bf16(a1, b, acc[1][nt], 0, 0, 0);
            }
            c0 = n0r; c1 = n1r;
        }
    } else {
        float v0[8], v1[8];
        *(float4*)&v0[0] = *(const float4*)(fa0);
        *(float4*)&v0[4] = *(const float4*)(fa0 + 4);
        *(float4*)&v1[0] = *(const float4*)(fa1);
        *(float4*)&v1[4] = *(const float4*)(fa1 + 4);
        for (int ks = 0; ks < ksteps; ++ks) {
            float w0[8], w1[8];
            if (ks + 1 < ksteps) {
                *(float4*)&w0[0] = *(const float4*)(fa0 + (ks + 1) * 32);
                *(float4*)&w0[4] = *(const float4*)(fa0 + (ks + 1) * 32 + 4);
                *(float4*)&w1[0] = *(const float4*)(fa1 + (ks + 1) * 32);
                *(float4*)&w1[4] = *(const float4*)(fa1 + (ks + 1) * 32 + 4);
            }
            short8 a0, a1;
            if (bn) {
                int c0i = ks * 32 + q * 8;
                float scv[8], shv[8];
                *(float4*)&scv[0] = *(const float4*)(bnsc + c0i);
                *(float4*)&scv[4] = *(const float4*)(bnsc + c0i + 4);
                *(float4*)&shv[0] = *(const float4*)(bnsh + c0i);
                *(float4*)&shv[4] = *(const float4*)(bnsh + c0i + 4);
                #pragma unroll
                for (int j = 0; j < 8; ++j) {
                    a0[j] = f2bf(fmaxf(fmaf(v0[j], scv[j], shv[j]), 0.f));
                    a1[j] = f2bf(fmaxf(fmaf(v1[j], scv[j], shv[j]), 0.f));
                }
            } else {
                #pragma unroll
                for (int j = 0; j < 8; ++j) { a0[j] = f2bf(v0[j]); a1[j] = f2bf(v1[j]); }
            }
            int idx = ks * 4;
            #pragma unroll
            for (int nt = 0; nt < 8; ++nt) {
                short8 b = pb[nt][idx];
                acc[0][nt] = __builtin_amdgcn_mfma_f32_16x16x32_bf16(a0, b, acc[0][nt], 0, 0, 0);
                acc[1][nt] = __builtin_amdgcn_mfma_f32_16x16x32_bf16(a1, b, acc[1][nt], 0, 0, 0);
            }
            #pragma unroll
            for (int j = 0; j < 8; ++j) { v0[j] = w0[j]; v1[j] = w1[j]; }
        }
    }

    float bv[8];
    int bmode = bias ? modes[bias_midx] : 0;
    #pragma unroll
    for (int nt = 0; nt < 8; ++nt)
        bv[nt] = bias ? loadf(bias, bmode, n0 + nt * 16 + m16) : 0.f;

    if (omode) {
        __shared__ unsigned short tile[64][136];    // half-tile, two passes
        __shared__ float redS[4][128], redQ[4][128];
        float sA[8], qA[8];
        #pragma unroll
        for (int nt = 0; nt < 8; ++nt) { sA[nt] = 0.f; qA[nt] = 0.f; }
        if (omode == 1) {
            #pragma unroll
            for (int mt = 0; mt < 2; ++mt)
                #pragma unroll
                for (int r = 0; r < 4; ++r) {
                    bool ok = (bm + mt * 16 + q * 4 + r) < M;
                    if (!ok) continue;
                    #pragma unroll
                    for (int nt = 0; nt < 8; ++nt) {
                        float v = acc[mt][nt][r] + bv[nt];
                        sA[nt] += v; qA[nt] += v * v;
                    }
                }
            #pragma unroll
            for (int nt = 0; nt < 8; ++nt) {
                sA[nt] += __shfl_xor(sA[nt], 16); sA[nt] += __shfl_xor(sA[nt], 32);
                qA[nt] += __shfl_xor(qA[nt], 16); qA[nt] += __shfl_xor(qA[nt], 32);
            }
            if (q == 0) {
                #pragma unroll
                for (int nt = 0; nt < 8; ++nt) {
                    redS[wv][nt * 16 + m16] = sA[nt];
                    redQ[wv][nt * 16 + m16] = qA[nt];
                }
            }
        }
        #pragma unroll
        for (int half = 0; half < 2; ++half) {
            if ((wv >> 1) == half) {
                int rbase = (wv & 1) * 32;
                #pragma unroll
                for (int mt = 0; mt < 2; ++mt)
                    #pragma unroll
                    for (int r = 0; r < 4; ++r) {
                        int rl = rbase + mt * 16 + q * 4 + r;
                        #pragma unroll
                        for (int nt = 0; nt < 8; ++nt) {
                            float v = acc[mt][nt][r] + bv[nt];
                            tile[rl][nt * 16 + m16] = (unsigned short)f2bf(v);
                        }
                    }
            }
            __syncthreads();
            int rb = blockIdx.y * 128 + half * 64;
            #pragma unroll
            for (int c = 0; c < 4; ++c) {
                int lin = c * 256 + tid;      // 16-byte unit index: 64 rows x 16 units
                int row = lin >> 4;
                int cu  = lin & 15;
                int grow = rb + row;
                if (grow < M)
                    *(short8*)(oB + (size_t)grow * N + n0 + cu * 8) = *(short8*)&tile[row][cu * 8];
            }
            __syncthreads();
        }
        if (omode == 1 && tid < 128) {
            float s = 0.f, qq = 0.f;
            #pragma unroll
            for (int w = 0; w < 4; ++w) { s += redS[w][tid]; qq += redQ[w][tid]; }
            float* dst = statsR + (blockIdx.y & (NREP - 1)) * 512;
            atomicAdd(&dst[n0 + tid], s);
            atomicAdd(&dst[256 + n0 + tid], qq);
        }
    } else {
        #pragma unroll
        for (int mt = 0; mt < 2; ++mt)
            #pragma unroll
            for (int r = 0; r < 4; ++r) {
                int row = bm + mt * 16 + q * 4 + r;
                if (row >= M) continue;
                #pragma unroll
                for (int nt = 0; nt < 8; ++nt)
                    outF[(size_t)row * N + n0 + nt * 16 + m16] = acc[mt][nt][r] + bv[nt];
            }
    }
}

// ---------------- BatchNorm ----------------
__global__ void bn_finalize(float* __restrict__ statsR, float* __restrict__ stats,
                            const void* __restrict__ g, const void* __restrict__ b,
                            const int* __restrict__ modes,
                            int gidx, int bidx, int C, float invM) {
    int c = threadIdx.x;
    if (c < C) {
        float s = 0.f, qq = 0.f;
        #pragma unroll
        for (int r = 0; r < NREP; ++r) {
            s  += statsR[r * 512 + c];
            qq += statsR[r * 512 + 256 + c];
        }
        float mean = s * invM;
        float var  = fmaxf(qq * invM - mean * mean, 0.f);
        float sc   = loadf(g, modes[gidx], c) * rsqrtf(var + 1e-5f);
        stats[2 * C + c] = sc;
        stats[3 * C + c] = loadf(b, modes[bidx], c) - mean * sc;
    }
    #pragma unroll
    for (int r = 0; r < NREP; ++r) {
        statsR[r * 512 + c] = 0.f;
        statsR[r * 512 + 256 + c] = 0.f;
    }
}

__global__ void bn_stats_f32(const float* __restrict__ X, float* __restrict__ statsR,
                             int M, int C, int rows) {
    int c = threadIdx.x;          // blockDim == C == 256
    int r0 = blockIdx.x * rows;
    int r1 = min(r0 + rows, M);
    float s = 0.f, s2 = 0.f;
    for (int r = r0; r < r1; ++r) {
        float v = X[(size_t)r * C + c];
        s += v; s2 += v * v;
    }
    float* dst = statsR + (blockIdx.x & (NREP - 1)) * 512;
    atomicAdd(&dst[c], s);
    atomicAdd(&dst[256 + c], s2);
}

// ---------------- GCN degree ----------------
__global__ void deg_scatter(const void* __restrict__ ew, const int* __restrict__ modes, int eidx,
                            const int* __restrict__ col, float* __restrict__ deg, int nE) {
    int e = blockIdx.x * blockDim.x + threadIdx.x;
    if (e < nE) atomicAdd(&deg[col[e]], loadf(ew, modes[eidx], e));
}

__global__ void dinv_fin(float* __restrict__ deg, int n) {
    int i = blockIdx.x * blockDim.x + threadIdx.x;
    if (i < n) {
        float d = deg[i] + 1.0f;
        deg[i] = d > 0.f ? rsqrtf(d) : 0.f;
    }
}

// ---------------- pooling ----------------
__global__ void pool_sorted_bf16(const unsigned short* __restrict__ xn,
                                 const int* __restrict__ batch,
                                 float* __restrict__ xg, int nN) {
    int g = blockIdx.x;
    int lo = 0, hi = nN;
    while (lo < hi) { int mid = (lo + hi) >> 1; if (batch[mid] < g) lo = mid + 1; else hi = mid; }
    int lo2 = lo, hi2 = nN;
    while (lo2 < hi2) { int mid = (lo2 + hi2) >> 1; if (batch[mid] < g + 1) lo2 = mid + 1; else hi2 = mid; }
    int d = threadIdx.x;          // 128
    float s = 0.f;
    for (int r = lo; r < lo2; ++r) s += bf2f((short)xn[(size_t)r * 128 + d]);
    xg[(size_t)g * 128 + d] = s / fmaxf((float)(lo2 - lo), 1.0f);
}

__global__ void svc_pool1(const float* __restrict__ xsl, float* __restrict__ partial) {
    int o = blockIdx.x;           // 50
    int c = blockIdx.y;           // 8
    int d = threadIdx.x;          // 128
    float s = 0.f;
    int r0 = c * 128;
    for (int r = r0; r < r0 + 128; ++r)
        s += xsl[((size_t)(r * 50 + o)) * 128 + d];
    partial[((size_t)(o * 8 + c)) * 128 + d] = s;
}

__global__ void svc_pool2(const float* __restrict__ partial, float* __restrict__ xsg) {
    int o = blockIdx.x;           // 50
    int d = threadIdx.x;          // 128
    float s = 0.f;
    #pragma unroll
    for (int c = 0; c < 8; ++c)
        s += partial[((size_t)(o * 8 + c)) * 128 + d];
    xsg[o * 128 + d] = s * (1.0f / 1024.0f);
}

// ---------------- final ----------------
__global__ void final_out(const float* __restrict__ xg, const float* __restrict__ xsg,
                          const int* __restrict__ modes, void* __restrict__ out) {
    __shared__ float xrow[128];
    int g = blockIdx.x;
    for (int d = threadIdx.x; d < 128; d += 64) xrow[d] = xg[(size_t)g * 128 + d];
    __syncthreads();
    int o = threadIdx.x;
    if (o < 50) {
        const float* xs = xsg + o * 128;
        float s = 0.f;
        #pragma unroll 4
        for (int d = 0; d < 128; ++d) s += xrow[d] * xs[d];
        float sg = 1.0f / (1.0f + __expf(-s));
        if (modes[0] == 1) ((bf16*)out)[(size_t)g * 50 + o] = __float2bfloat16(sg);
        else               ((float*)out)[(size_t)g * 50 + o] = sg;
    }
}

extern "C" void kernel_launch(void* const* d_in, const int* in_sizes, int n_in,
                              void* d_out, int out_size, void* d_ws, size_t ws_size,
                              hipStream_t stream) {
    const int nN = 100000, nE = 800000, nS = 51200, nES = 409600;
    const int Bg = 1024;

    const int* node_ids = (const int*)d_in[0];
    const int* ei       = (const int*)d_in[2];
    const int* svc_ids  = (const int*)d_in[3];
    const int* eis      = (const int*)d_in[5];
    const int* batch    = (const int*)d_in[7];

    // ---------------- workspace layout (float words, 16B-aligned blocks) ----------------
    float* ws    = (float*)d_ws;
    int*   modes = (int*)ws;                        // 64
    float* stats = ws + 64;                         // 1024 (sc/sh only)
    float* dinv  = ws + 1088;                       // 51200
    float* xsg   = ws + 52288;                      // 6400
    int*   bsum  = (int*)(ws + 58688);              // 256
    int*   rp_n  = (int*)(ws + 58944);              // 100001
    int*   adj_n = (int*)(ws + 158948);             // 800000
    int*   rp_s  = (int*)(ws + 958948);             // 51201
    int*   adj_s = (int*)(ws + 1010152);            // 409600
    short* adw_s = (short*)(ws + 1419752);          // 409600 shorts
    short* wtb   = (short*)(ws + 1624552);          // 262144 shorts
    float* xg    = ws + 1755624;                    // 131072 (also cur_n early)
    float* part  = ws + 1886696;                    // 51200  (also cur_s early)
    float* A25   = ws + 1937896;                    // 25,600,000 (only ~13.11M used)
    float* B13   = ws + 27537896;                   // 13,107,200
    float* C13   = ws + 40645096;                   // 13,107,200
    size_t need  = (size_t)53752296 * 4;
    if (ws_size < need) return;
    int* cur_n = (int*)xg;
    int* cur_s = (int*)part;
    int* bsum_n = bsum;
    int* bsum_s = bsum + 128;
    float* statsR = A25 + 13200000;                 // NREP*512 = 8192 floats

    unsigned short* A25B = (unsigned short*)A25;
    unsigned short* B13B = (unsigned short*)B13;
    unsigned short* C13B = (unsigned short*)C13;
    float* B13F = B13;  float* A25F = A25;

    // BN sc/sh locations inside stats: C=256 -> sc@512, sh@768 ; C=128 -> sc@256, sh@384
    float* sc256 = stats + 512; float* sh256 = stats + 768;
    float* sc128 = stats + 256; float* sh128 = stats + 384;

    short* wt0 = wtb;               // g0_W1  256 x 96
    short* wt1 = wt0 + 24576;       // g0_W2  128 x 256
    short* wt2 = wt1 + 32768;       // g1_W1  256 x 128
    short* wt3 = wt2 + 32768;       // g1_W2  128 x 256
    short* wt4 = wt3 + 32768;       // nl_W   128 x 128
    short* wt5 = wt4 + 16384;       // c0_W   256 x 96
    short* wt6 = wt5 + 24576;       // c1_W   256 x 256
    short* wt7 = wt6 + 65536;       // sl_W   128 x 256

    // ---------------- detect dtypes (once, 35 blocks) ----------------
    static const int conv_idx[NCONV] = {1, 4, 6, 10, 11,
        12, 13, 14, 15, 16, 17, 18, 19, 20,
        21, 22, 23, 24, 25, 26, 27, 28, 29,
        30, 31, 32, 33, 34, 35, 36, 37, 38, 39, 40, 41};
    DetArgs da;
    for (int b = 0; b < NCONV; ++b) { da.src[b] = d_in[conv_idx[b]]; da.n[b] = in_sizes[conv_idx[b]]; }
    detect_all<<<NCONV, 256, 0, stream>>>(da, modes);

    // initial zero of replicated stats (folds re-zero after each use)
    hipMemsetAsync(statsR, 0, NREP * 512 * sizeof(float), stream);

    // ---------------- weight transposes (batched) ----------------
    {
        WtArgs wa;
        const int din_i[8]  = {12, 16, 21, 25, 30, 32, 36, 40};
        const int midx_i[8] = {5, 9, 14, 18, 23, 25, 29, 33};
        const int KW_i[8]   = {70, 256, 128, 256, 128, 68, 256, 256};
        const int ldw_i[8]  = {256, 128, 256, 128, 128, 256, 256, 128};
        short* wt_i[8]      = {wt0, wt1, wt2, wt3, wt4, wt5, wt6, wt7};
        const int Kp_i[8]   = {96, 256, 128, 256, 128, 96, 256, 256};
        const int N_i[8]    = {256, 128, 256, 128, 128, 256, 256, 128};
        for (int e = 0; e < 8; ++e) {
            wa.W[e] = d_in[din_i[e]]; wa.midx[e] = midx_i[e]; wa.KW[e] = KW_i[e];
            wa.ldw[e] = ldw_i[e]; wa.wt[e] = wt_i[e]; wa.Kpad[e] = Kp_i[e]; wa.N[e] = N_i[e];
        }
        wt_build_all<<<dim3(256, 8), 256, 0, stream>>>(wa, modes);
    }

    // ---------------- degrees (before CSR fill so adjw can fold dinv) ----------------
    hipMemsetAsync(dinv, 0, nS * sizeof(float), stream);
    deg_scatter<<<(nES + 255) / 256, 256, 0, stream>>>(d_in[6], modes, 2, eis + nES, dinv, nES);
    dinv_fin<<<(nS + 255) / 256, 256, 0, stream>>>(dinv, nS);

    // ---------------- CSR builds (hierarchical scan) ----------------
    const int nbN = (nN + 1023) / 1024, nbS = (nS + 1023) / 1024;
    hipMemsetAsync(cur_n, 0, nN * sizeof(int), stream);
    csr_count<<<(nE + 255) / 256, 256, 0, stream>>>(ei + nE, nE, cur_n);
    scan_part<<<nbN, 256, 0, stream>>>(cur_n, nN, bsum_n);
    scan_mid<<<1, 128, 0, stream>>>(bsum_n, nbN, rp_n, nN);
    scan_fin<<<nbN, 256, 0, stream>>>(cur_n, nN, bsum_n, rp_n, cur_n);
    csr_fill<<<(nE + 255) / 256, 256, 0, stream>>>(ei, ei + nE, nullptr, modes, 2, nullptr,
                                                   nE, cur_n, adj_n, nullptr);

    hipMemsetAsync(cur_s, 0, nS * sizeof(int), stream);
    csr_count<<<(nES + 255) / 256, 256, 0, stream>>>(eis + nES, nES, cur_s);
    scan_part<<<nbS, 256, 0, stream>>>(cur_s, nS, bsum_s);
    scan_mid<<<1, 128, 0, stream>>>(bsum_s, nbS, rp_s, nS);
    scan_fin<<<nbS, 256, 0, stream>>>(cur_s, nS, bsum_s, rp_s, cur_s);
    csr_fill<<<(nES + 255) / 256, 256, 0, stream>>>(eis, eis + nES, d_in[6], modes, 2, dinv,
                                                    nES, cur_s, adj_s, adw_s);

    auto gemm = [&](const void* A, int afmt, int ldk, const float* bsc, const float* bsh,
                    const short* Wt, const void* bias, int bidx,
                    float* outF, unsigned short* oB, int M, int N, int om) {
        dim3 grid(N / 128, (M + 127) / 128);
        gemm_mfma<<<grid, 256, 0, stream>>>(A, afmt, ldk, bsc, bsh, Wt, bias, modes, bidx,
                                            outF, oB, statsR, M, N, ldk / 32, om);
    };
    auto bnfin = [&](int gidx, int bidx, const void* g, const void* b, int C, int M) {
        bn_finalize<<<1, 256, 0, stream>>>(statsR, stats, g, b, modes, gidx, bidx, C, 1.0f / M);
    };

    // ---------------- node branch ----------------
    build_feat_bf16<<<nN, 128, 0, stream>>>(d_in[10], node_ids, d_in[1], modes, 3, 0,
                                            C13B, 6, 96);
    gin_gather_bf16<<<(nN + 15) / 16, 256, 0, stream>>>(C13B, rp_n, adj_n, d_in[18], modes, 11,
                                                        nullptr, nullptr, B13B, 96, nN);
    gemm(B13B, 0, 96, nullptr, nullptr, wt0, d_in[13], 6, nullptr, A25B, nN, 256, 1);
    bnfin(7, 8, d_in[14], d_in[15], 256, nN);                       // BN1 -> sc256/sh256
    gemm(A25B, 0, 256, sc256, sh256, wt1, d_in[17], 10, nullptr, C13B, nN, 128, 1);
    bnfin(12, 13, d_in[19], d_in[20], 128, nN);                     // BN2 -> sc128/sh128
    gin_gather_bf16<<<(nN + 15) / 16, 256, 0, stream>>>(C13B, rp_n, adj_n, d_in[27], modes, 20,
                                                        sc128, sh128, B13B, 128, nN);
    gemm(B13B, 0, 128, nullptr, nullptr, wt2, d_in[22], 15, nullptr, A25B, nN, 256, 1);
    bnfin(16, 17, d_in[23], d_in[24], 256, nN);                     // BN3
    gemm(A25B, 0, 256, sc256, sh256, wt3, d_in[26], 19, nullptr, C13B, nN, 128, 1);
    bnfin(21, 22, d_in[28], d_in[29], 128, nN);                     // BN4
    gemm(C13B, 0, 128, sc128, sh128, wt4, d_in[31], 24, nullptr, B13B, nN, 128, 2);
    pool_sorted_bf16<<<Bg, 128, 0, stream>>>(B13B, batch, xg, nN);

    // ---------------- service branch ----------------
    build_feat_bf16<<<nS, 128, 0, stream>>>(d_in[11], svc_ids, d_in[4], modes, 4, 1,
                                            C13B, 4, 96);
    gemm(C13B, 0, 96, nullptr, nullptr, wt5, nullptr, 0, nullptr, B13B, nS, 256, 2);
    gcn_gather_bf16<<<(nS + 7) / 8, 256, 0, stream>>>(B13B, rp_s, adj_s, adw_s, dinv, d_in[33],
                                                      modes, 26, A25F, nS);
    bn_stats_f32<<<(nS + 31) / 32, 256, 0, stream>>>(A25F, statsR, nS, 256, 32);
    bnfin(27, 28, d_in[34], d_in[35], 256, nS);
    gemm(A25F, 1, 256, sc256, sh256, wt6, nullptr, 0, nullptr, B13B, nS, 256, 2);
    gcn_gather_bf16<<<(nS + 7) / 8, 256, 0, stream>>>(B13B, rp_s, adj_s, adw_s, dinv, d_in[37],
                                                      modes, 30, A25F, nS);
    bn_stats_f32<<<(nS + 31) / 32, 256, 0, stream>>>(A25F, statsR, nS, 256, 32);
    bnfin(31, 32, d_in[38], d_in[39], 256, nS);
    gemm(A25F, 1, 256, sc256, sh256, wt7, d_in[41], 34, B13F, nullptr, nS, 128, 0);
    svc_pool1<<<dim3(50, 8), 128, 0, stream>>>(B13F, part);
    svc_pool2<<<50, 128, 0, stream>>>(part, xsg);

    // ---------------- output ----------------
    final_out<<<Bg, 64, 0, stream>>>(xg, xsg, modes, d_out);
}

// Round 16
// 997.805 us; speedup vs baseline: 1.0117x; 1.0117x over previous
//
#include <hip/hip_runtime.h>
#include <hip/hip_bf16.h>
#include <cstddef>
#include <cstdint>

typedef __hip_bfloat16 bf16;
typedef __attribute__((ext_vector_type(8))) short short8;      // 8 bf16 (4 VGPRs)
typedef __attribute__((ext_vector_type(4))) float floatx4;     // MFMA acc

static __device__ __forceinline__ float b2f(bf16 v) { return __bfloat162float(v); }

static __device__ __forceinline__ short f2bf(float f) {
    unsigned u = __float_as_uint(f);
    unsigned r = u + 0x7FFF + ((u >> 16) & 1);
    return (short)(r >> 16);
}
static __device__ __forceinline__ float bf2f(short h) {
    return __uint_as_float(((unsigned)(unsigned short)h) << 16);
}
// mode: 0=zero, 1=bf16-stored, 2=fp32-stored
static __device__ __forceinline__ float loadf(const void* p, int mode, size_t i) {
    if (mode == 1) return b2f(((const bf16*)p)[i]);
    if (mode == 2) return ((const float*)p)[i];
    return 0.f;
}

#define NCONV 35
#define NREP 16
struct DetArgs { const void* src[NCONV]; int n[NCONV]; };

// ---------------- dtype detection (one block per buffer) ----------------
__global__ void detect_all(DetArgs a, int* __restrict__ modes) {
    int b = blockIdx.x;
    int n = a.n[b];
    const unsigned short* w = (const unsigned short*)a.src[b];
    __shared__ int cz, cbad, cevz, codz;
    if (threadIdx.x == 0) { cz = 0; cbad = 0; cevz = 0; codz = 0; }
    __syncthreads();
    int K = n < 2048 ? n : 2048;
    int z = 0, bad = 0, evz = 0, odz = 0;
    for (int i = threadIdx.x; i < K; i += blockDim.x) {
        unsigned short v = w[i];
        int e = (v >> 7) & 0xFF;
        bool isz = (v & 0x7FFF) == 0;
        if (isz) { z++; if (i & 1) odz++; else evz++; }
        else if (e < 91 || e > 140) bad++;
    }
    atomicAdd(&cz, z); atomicAdd(&cbad, bad);
    atomicAdd(&cevz, evz); atomicAdd(&codz, odz);
    __syncthreads();
    if (threadIdx.x == 0) {
        int mode;
        if (cz >= K) mode = 0;
        else if (cbad * 16 > K) mode = 2;
        else if (cevz * 4 > K && codz * 16 < K) mode = 2;
        else mode = 1;
        modes[b] = mode;
    }
}

// ---------------- batched weight transpose -> bf16 Wt[n][Kpad] ----------------
struct WtArgs {
    const void* W[8]; short* wt[8];
    int midx[8]; int KW[8]; int ldw[8]; int Kpad[8]; int N[8];
};
__global__ void wt_build_all(WtArgs a, const int* __restrict__ modes) {
    int e = blockIdx.y;
    int n = blockIdx.x; if (n >= a.N[e]) return;
    int k = threadIdx.x; if (k >= a.Kpad[e]) return;
    float v = (k < a.KW[e]) ? loadf(a.W[e], modes[a.midx[e]], (size_t)k * a.ldw[e] + n) : 0.f;
    a.wt[e][(size_t)n * a.Kpad[e] + k] = f2bf(v);
}

// ---------------- feature build -> bf16 plane ----------------
__global__ void build_feat_bf16(const void* __restrict__ emb, const int* __restrict__ ids,
                                const void* __restrict__ feats, const int* __restrict__ modes,
                                int eidx, int fidx, unsigned short* __restrict__ P,
                                int nf, int Ws) {
    int i = blockIdx.x;
    int d = threadIdx.x;          // 128
    if (d >= Ws) return;
    float v;
    if (d < 64)           v = loadf(emb, modes[eidx], (size_t)ids[i] * 64 + d);
    else if (d < 64 + nf) v = loadf(feats, modes[fidx], (size_t)i * nf + (d - 64));
    else                  v = 0.f;
    P[(size_t)i * Ws + d] = (unsigned short)f2bf(v);
}

// ---------------- CSR build ----------------
__global__ void csr_count(const int* __restrict__ dst, int nE, int* __restrict__ cnt) {
    int e = blockIdx.x * blockDim.x + threadIdx.x;
    if (e < nE) atomicAdd(&cnt[dst[e]], 1);
}

__global__ __launch_bounds__(256) void scan_part(const int* __restrict__ cnt, int n,
                                                 int* __restrict__ bsum) {
    __shared__ int red[256];
    int blk = blockIdx.x, t = threadIdx.x;
    int base = blk * 1024 + t * 4;
    int s = 0;
    #pragma unroll
    for (int k = 0; k < 4; ++k) { int i = base + k; if (i < n) s += cnt[i]; }
    red[t] = s;
    __syncthreads();
    for (int off = 128; off > 0; off >>= 1) {
        if (t < off) red[t] += red[t + off];
        __syncthreads();
    }
    if (t == 0) bsum[blk] = red[0];
}

__global__ __launch_bounds__(128) void scan_mid(int* __restrict__ bsum, int nb,
                                                int* __restrict__ rowptr, int n) {
    __shared__ int sh[128];
    int t = threadIdx.x;
    int v = (t < nb) ? bsum[t] : 0;
    sh[t] = v;
    __syncthreads();
    for (int off = 1; off < 128; off <<= 1) {
        int u = (t >= off) ? sh[t - off] : 0;
        __syncthreads();
        sh[t] += u;
        __syncthreads();
    }
    if (t < nb) bsum[t] = sh[t] - v;        // exclusive
    if (t == 127) rowptr[n] = sh[127];      // total
}

__global__ __launch_bounds__(256) void scan_fin(const int* __restrict__ cnt, int n,
                                                const int* __restrict__ bsum,
                                                int* __restrict__ rowptr, int* __restrict__ cursor) {
    __shared__ int sh[256];
    int blk = blockIdx.x, t = threadIdx.x;
    int base = blk * 1024 + t * 4;
    int v[4], s = 0;
    #pragma unroll
    for (int k = 0; k < 4; ++k) { int i = base + k; v[k] = (i < n) ? cnt[i] : 0; s += v[k]; }
    sh[t] = s;
    __syncthreads();
    for (int off = 1; off < 256; off <<= 1) {
        int u = (t >= off) ? sh[t - off] : 0;
        __syncthreads();
        sh[t] += u;
        __syncthreads();
    }
    int run = sh[t] - s + bsum[blk];
    #pragma unroll
    for (int k = 0; k < 4; ++k) {
        int i = base + k;
        if (i < n) { rowptr[i] = run; cursor[i] = run; run += v[k]; }
    }
}

__global__ void csr_fill(const int* __restrict__ src, const int* __restrict__ dst,
                         const void* __restrict__ w, const int* __restrict__ modes, int widx,
                         const float* __restrict__ dinv, int nE, int* __restrict__ cursor,
                         int* __restrict__ adj, short* __restrict__ adjw) {
    int e = blockIdx.x * blockDim.x + threadIdx.x;
    if (e < nE) {
        int s = src[e];
        int pos = atomicAdd(&cursor[dst[e]], 1);
        adj[pos] = s;
        if (adjw) adjw[pos] = f2bf(dinv[s] * loadf(w, modes[widx], e));
    }
}

// ---------------- GIN gather, bf16, 16-lane groups, optional fused BN+ReLU ----------------
__global__ __launch_bounds__(256) void gin_gather_bf16(
        const unsigned short* __restrict__ P, const int* __restrict__ rowptr,
        const int* __restrict__ adj, const void* __restrict__ eps,
        const int* __restrict__ modes, int eidx,
        const float* __restrict__ bnsc, const float* __restrict__ bnsh,
        unsigned short* __restrict__ Po, int Ws, int nN) {
    int W8 = Ws >> 3;
    int g = threadIdx.x >> 4;                 // 16 row-groups per block
    int l = threadIdx.x & 15;                 // lane in group
    int i = blockIdx.x * 16 + g;
    if (i >= nN || l >= W8) return;
    float epsv = 1.0f + loadf(eps, modes[eidx], 0);
    float sc[8], sh[8];
    bool bn = bnsc != nullptr;
    if (bn) {
        *(float4*)&sc[0] = *(const float4*)(bnsc + l * 8);
        *(float4*)&sc[4] = *(const float4*)(bnsc + l * 8 + 4);
        *(float4*)&sh[0] = *(const float4*)(bnsh + l * 8);
        *(float4*)&sh[4] = *(const float4*)(bnsh + l * 8 + 4);
    }
    int lo = rowptr[i], hi = rowptr[i + 1];
    float acc[8] = {};
    for (int p = lo; p < hi; ++p) {
        short8 v = *(const short8*)(P + (size_t)adj[p] * Ws + l * 8);
        #pragma unroll
        for (int j = 0; j < 8; ++j) {
            float y = bf2f(v[j]);
            if (bn) y = fmaxf(fmaf(y, sc[j], sh[j]), 0.f);
            acc[j] += y;
        }
    }
    size_t o = (size_t)i * Ws + l * 8;
    short8 sv = *(const short8*)(P + o);
    short8 r;
    #pragma unroll
    for (int j = 0; j < 8; ++j) {
        float y = bf2f(sv[j]);
        if (bn) y = fmaxf(fmaf(y, sc[j], sh[j]), 0.f);
        r[j] = f2bf(acc[j] + epsv * y);
    }
    *(short8*)(Po + o) = r;
}

// ---------------- GCN gather, bf16 input xw, fp32 output ----------------
__global__ __launch_bounds__(256) void gcn_gather_bf16(
        const unsigned short* __restrict__ xw, const int* __restrict__ rowptr,
        const int* __restrict__ adj, const short* __restrict__ adjw,
        const float* __restrict__ dinv, const void* __restrict__ bias,
        const int* __restrict__ modes, int bidx, float* __restrict__ out, int nS) {
    int g = threadIdx.x >> 5;                 // 8 groups
    int l = threadIdx.x & 31;                 // 32 lanes x 8 cols = 256
    int i = blockIdx.x * 8 + g;
    if (i >= nS) return;
    float di = dinv[i];
    int bmode = modes[bidx];
    size_t o = (size_t)i * 256 + l * 8;
    short8 sv = *(const short8*)(xw + o);
    float dd = di * di;
    float acc[8];
    #pragma unroll
    for (int j = 0; j < 8; ++j)
        acc[j] = bf2f(sv[j]) * dd + loadf(bias, bmode, l * 8 + j);
    int lo = rowptr[i], hi = rowptr[i + 1];
    for (int p = lo; p < hi; ++p) {
        float w = di * bf2f(adjw[p]);
        short8 v = *(const short8*)(xw + (size_t)adj[p] * 256 + l * 8);
        #pragma unroll
        for (int j = 0; j < 8; ++j)
            acc[j] += w * bf2f(v[j]);
    }
    *(float4*)(out + o) = *(float4*)&acc[0];
    *(float4*)(out + o + 4) = *(float4*)&acc[4];
}

// ---------------- MFMA GEMM (unroll-2, replicated stats): out[M,N] = f(A)[M,ldk] @ Wt^T ----
// afmt: 0 = bf16, 1 = fp32.  bnsc/bnsh non-null: A' = relu(A*sc+sh).
// omode: 0 = fp32 out (+bias); 1 = bf16 out + replicated column stats; 2 = bf16 out
__global__ __launch_bounds__(256) void gemm_mfma(
        const void* __restrict__ A, int afmt, int ldk,
        const float* __restrict__ bnsc, const float* __restrict__ bnsh,
        const short* __restrict__ Wt,
        const void* __restrict__ bias, const int* __restrict__ modes, int bias_midx,
        float* __restrict__ outF, unsigned short* __restrict__ oB,
        float* __restrict__ statsR, int M, int N, int ksteps, int omode) {
    int tid  = threadIdx.x;
    int wv   = tid >> 6, lane = tid & 63;
    int m16  = lane & 15, q = lane >> 4;
    int bm   = blockIdx.y * 128 + wv * 32;
    int n0   = blockIdx.x * 128;
    int r0 = min(bm + m16, M - 1);
    int r1 = min(bm + 16 + m16, M - 1);
    const short8* ba0 = (const short8*)((const short*)A + (size_t)r0 * ldk + q * 8);
    const short8* ba1 = (const short8*)((const short*)A + (size_t)r1 * ldk + q * 8);
    const float*  fa0 = (const float*)A + (size_t)r0 * ldk + q * 8;
    const float*  fa1 = (const float*)A + (size_t)r1 * ldk + q * 8;
    const short8* pb[8];
    #pragma unroll
    for (int nt = 0; nt < 8; ++nt)
        pb[nt] = (const short8*)(Wt + (size_t)(n0 + nt * 16 + m16) * ldk + q * 8);

    floatx4 acc[2][8];
    #pragma unroll
    for (int mt = 0; mt < 2; ++mt)
        #pragma unroll
        for (int nt = 0; nt < 8; ++nt)
            acc[mt][nt] = (floatx4){0.f, 0.f, 0.f, 0.f};

    bool bn = bnsc != nullptr;

    if (afmt == 0) {
        // unroll-2: issue both k-steps' A loads before any convert/MFMA work
        for (int ks = 0; ks < ksteps; ks += 2) {
            bool two = (ks + 1) < ksteps;
            int i0 = ks * 4, i1 = two ? i0 + 4 : i0;
            short8 u00 = ba0[i0], u10 = ba1[i0];
            short8 u01 = ba0[i1], u11 = ba1[i1];
            #pragma unroll
            for (int u = 0; u < 2; ++u) {
                if (u == 1 && !two) break;
                short8 ra0 = u ? u01 : u00, ra1 = u ? u11 : u10;
                short8 a0, a1;
                if (!bn) { a0 = ra0; a1 = ra1; }
                else {
                    int c0 = (ks + u) * 32 + q * 8;
                    float v0[8], v1[8], scv[8], shv[8];
                    #pragma unroll
                    for (int j = 0; j < 8; ++j) { v0[j] = bf2f(ra0[j]); v1[j] = bf2f(ra1[j]); }
                    *(float4*)&scv[0] = *(const float4*)(bnsc + c0);
                    *(float4*)&scv[4] = *(const float4*)(bnsc + c0 + 4);
                    *(float4*)&shv[0] = *(const float4*)(bnsh + c0);
                    *(float4*)&shv[4] = *(const float4*)(bnsh + c0 + 4);
                    #pragma unroll
                    for (int j = 0; j < 8; ++j) {
                        a0[j] = f2bf(fmaxf(fmaf(v0[j], scv[j], shv[j]), 0.f));
                        a1[j] = f2bf(fmaxf(fmaf(v1[j], scv[j], shv[j]), 0.f));
                    }
                }
                int idx = (ks + u) * 4;
                #pragma unroll
                for (int nt = 0; nt < 8; ++nt) {
                    short8 b = pb[nt][idx];
                    acc[0][nt] = __builtin_amdgcn_mfma_f32_16x16x32_bf16(a0, b, acc[0][nt], 0, 0, 0);
                    acc[1][nt] = __builtin_amdgcn_mfma_f32_16x16x32_bf16(a1, b, acc[1][nt], 0, 0, 0);
                }
            }
        }
    } else {
        for (int ks = 0; ks < ksteps; ++ks) {
            int idx = ks * 4;
            short8 a0, a1;
            float v0[8], v1[8];
            *(float4*)&v0[0] = *(const float4*)(fa0 + ks * 32);
            *(float4*)&v0[4] = *(const float4*)(fa0 + ks * 32 + 4);
            *(float4*)&v1[0] = *(const float4*)(fa1 + ks * 32);
            *(float4*)&v1[4] = *(const float4*)(fa1 + ks * 32 + 4);
            if (bn) {
                int c0 = ks * 32 + q * 8;
                float scv[8], shv[8];
                *(float4*)&scv[0] = *(const float4*)(bnsc + c0);
                *(float4*)&scv[4] = *(const float4*)(bnsc + c0 + 4);
                *(float4*)&shv[0] = *(const float4*)(bnsh + c0);
                *(float4*)&shv[4] = *(const float4*)(bnsh + c0 + 4);
                #pragma unroll
                for (int j = 0; j < 8; ++j) {
                    v0[j] = fmaxf(fmaf(v0[j], scv[j], shv[j]), 0.f);
                    v1[j] = fmaxf(fmaf(v1[j], scv[j], shv[j]), 0.f);
                }
            }
            #pragma unroll
            for (int j = 0; j < 8; ++j) { a0[j] = f2bf(v0[j]); a1[j] = f2bf(v1[j]); }
            #pragma unroll
            for (int nt = 0; nt < 8; ++nt) {
                short8 b = pb[nt][idx];
                acc[0][nt] = __builtin_amdgcn_mfma_f32_16x16x32_bf16(a0, b, acc[0][nt], 0, 0, 0);
                acc[1][nt] = __builtin_amdgcn_mfma_f32_16x16x32_bf16(a1, b, acc[1][nt], 0, 0, 0);
            }
        }
    }

    float bv[8];
    int bmode = bias ? modes[bias_midx] : 0;
    #pragma unroll
    for (int nt = 0; nt < 8; ++nt)
        bv[nt] = bias ? loadf(bias, bmode, n0 + nt * 16 + m16) : 0.f;

    if (omode) {
        __shared__ unsigned short tile[128][136];   // padded: quad rows 8 banks apart
        __shared__ float redS[4][128], redQ[4][128];
        float sA[8], qA[8];
        #pragma unroll
        for (int nt = 0; nt < 8; ++nt) { sA[nt] = 0.f; qA[nt] = 0.f; }
        #pragma unroll
        for (int mt = 0; mt < 2; ++mt)
            #pragma unroll
            for (int r = 0; r < 4; ++r) {
                int rl = wv * 32 + mt * 16 + q * 4 + r;
                bool ok = (bm + mt * 16 + q * 4 + r) < M;
                #pragma unroll
                for (int nt = 0; nt < 8; ++nt) {
                    float v = acc[mt][nt][r] + bv[nt];
                    tile[rl][nt * 16 + m16] = (unsigned short)f2bf(v);
                    if (ok && omode == 1) { sA[nt] += v; qA[nt] += v * v; }
                }
            }
        if (omode == 1) {
            #pragma unroll
            for (int nt = 0; nt < 8; ++nt) {
                sA[nt] += __shfl_xor(sA[nt], 16); sA[nt] += __shfl_xor(sA[nt], 32);
                qA[nt] += __shfl_xor(qA[nt], 16); qA[nt] += __shfl_xor(qA[nt], 32);
            }
            if (q == 0) {
                #pragma unroll
                for (int nt = 0; nt < 8; ++nt) {
                    redS[wv][nt * 16 + m16] = sA[nt];
                    redQ[wv][nt * 16 + m16] = qA[nt];
                }
            }
        }
        __syncthreads();
        int rb = blockIdx.y * 128;
        #pragma unroll
        for (int c = 0; c < 8; ++c) {
            int lin = c * 256 + tid;      // 16-byte unit index
            int row = lin >> 4;
            int cu  = lin & 15;
            int grow = rb + row;
            if (grow < M)
                *(short8*)(oB + (size_t)grow * N + n0 + cu * 8) = *(short8*)&tile[row][cu * 8];
        }
        if (omode == 1 && tid < 128) {
            float s = 0.f, qq = 0.f;
            #pragma unroll
            for (int w = 0; w < 4; ++w) { s += redS[w][tid]; qq += redQ[w][tid]; }
            float* dst = statsR + (blockIdx.y & (NREP - 1)) * 512;
            atomicAdd(&dst[n0 + tid], s);
            atomicAdd(&dst[256 + n0 + tid], qq);
        }
    } else {
        #pragma unroll
        for (int mt = 0; mt < 2; ++mt)
            #pragma unroll
            for (int r = 0; r < 4; ++r) {
                int row = bm + mt * 16 + q * 4 + r;
                if (row >= M) continue;
                #pragma unroll
                for (int nt = 0; nt < 8; ++nt)
                    outF[(size_t)row * N + n0 + nt * 16 + m16] = acc[mt][nt][r] + bv[nt];
            }
    }
}

// ---------------- BatchNorm ----------------
// folds NREP replicas from statsR, writes sc/sh into stats[2C+..], stats[3C+..]
__global__ void bn_finalize(const float* __restrict__ statsR, float* __restrict__ stats,
                            const void* __restrict__ g, const void* __restrict__ b,
                            const int* __restrict__ modes,
                            int gidx, int bidx, int C, float invM) {
    int c = threadIdx.x;
    if (c < C) {
        float s = 0.f, qq = 0.f;
        #pragma unroll
        for (int r = 0; r < NREP; ++r) {
            s  += statsR[r * 512 + c];
            qq += statsR[r * 512 + 256 + c];
        }
        float mean = s * invM;
        float var  = fmaxf(qq * invM - mean * mean, 0.f);
        float sc   = loadf(g, modes[gidx], c) * rsqrtf(var + 1e-5f);
        stats[2 * C + c] = sc;
        stats[3 * C + c] = loadf(b, modes[bidx], c) - mean * sc;
    }
}

__global__ void bn_stats_f32(const float* __restrict__ X, float* __restrict__ statsR,
                             int M, int C, int rows) {
    int c = threadIdx.x;          // blockDim == C == 256
    int r0 = blockIdx.x * rows;
    int r1 = min(r0 + rows, M);
    float s = 0.f, s2 = 0.f;
    for (int r = r0; r < r1; ++r) {
        float v = X[(size_t)r * C + c];
        s += v; s2 += v * v;
    }
    float* dst = statsR + (blockIdx.x & (NREP - 1)) * 512;
    atomicAdd(&dst[c], s);
    atomicAdd(&dst[256 + c], s2);
}

// ---------------- GCN degree ----------------
__global__ void deg_scatter(const void* __restrict__ ew, const int* __restrict__ modes, int eidx,
                            const int* __restrict__ col, float* __restrict__ deg, int nE) {
    int e = blockIdx.x * blockDim.x + threadIdx.x;
    if (e < nE) atomicAdd(&deg[col[e]], loadf(ew, modes[eidx], e));
}

__global__ void dinv_fin(float* __restrict__ deg, int n) {
    int i = blockIdx.x * blockDim.x + threadIdx.x;
    if (i < n) {
        float d = deg[i] + 1.0f;
        deg[i] = d > 0.f ? rsqrtf(d) : 0.f;
    }
}

// ---------------- pooling ----------------
__global__ void pool_sorted_bf16(const unsigned short* __restrict__ xn,
                                 const int* __restrict__ batch,
                                 float* __restrict__ xg, int nN) {
    int g = blockIdx.x;
    int lo = 0, hi = nN;
    while (lo < hi) { int mid = (lo + hi) >> 1; if (batch[mid] < g) lo = mid + 1; else hi = mid; }
    int lo2 = lo, hi2 = nN;
    while (lo2 < hi2) { int mid = (lo2 + hi2) >> 1; if (batch[mid] < g + 1) lo2 = mid + 1; else hi2 = mid; }
    int d = threadIdx.x;          // 128
    float s = 0.f;
    for (int r = lo; r < lo2; ++r) s += bf2f((short)xn[(size_t)r * 128 + d]);
    xg[(size_t)g * 128 + d] = s / fmaxf((float)(lo2 - lo), 1.0f);
}

__global__ void svc_pool1(const float* __restrict__ xsl, float* __restrict__ partial) {
    int o = blockIdx.x;           // 50
    int c = blockIdx.y;           // 8
    int d = threadIdx.x;          // 128
    float s = 0.f;
    int r0 = c * 128;
    for (int r = r0; r < r0 + 128; ++r)
        s += xsl[((size_t)(r * 50 + o)) * 128 + d];
    partial[((size_t)(o * 8 + c)) * 128 + d] = s;
}

__global__ void svc_pool2(const float* __restrict__ partial, float* __restrict__ xsg) {
    int o = blockIdx.x;           // 50
    int d = threadIdx.x;          // 128
    float s = 0.f;
    #pragma unroll
    for (int c = 0; c < 8; ++c)
        s += partial[((size_t)(o * 8 + c)) * 128 + d];
    xsg[o * 128 + d] = s * (1.0f / 1024.0f);
}

// ---------------- final ----------------
__global__ void final_out(const float* __restrict__ xg, const float* __restrict__ xsg,
                          const int* __restrict__ modes, void* __restrict__ out) {
    __shared__ float xrow[128];
    int g = blockIdx.x;
    for (int d = threadIdx.x; d < 128; d += 64) xrow[d] = xg[(size_t)g * 128 + d];
    __syncthreads();
    int o = threadIdx.x;
    if (o < 50) {
        const float* xs = xsg + o * 128;
        float s = 0.f;
        #pragma unroll 4
        for (int d = 0; d < 128; ++d) s += xrow[d] * xs[d];
        float sg = 1.0f / (1.0f + __expf(-s));
        if (modes[0] == 1) ((bf16*)out)[(size_t)g * 50 + o] = __float2bfloat16(sg);
        else               ((float*)out)[(size_t)g * 50 + o] = sg;
    }
}

extern "C" void kernel_launch(void* const* d_in, const int* in_sizes, int n_in,
                              void* d_out, int out_size, void* d_ws, size_t ws_size,
                              hipStream_t stream) {
    const int nN = 100000, nE = 800000, nS = 51200, nES = 409600;
    const int Bg = 1024;

    const int* node_ids = (const int*)d_in[0];
    const int* ei       = (const int*)d_in[2];
    const int* svc_ids  = (const int*)d_in[3];
    const int* eis      = (const int*)d_in[5];
    const int* batch    = (const int*)d_in[7];

    // ---------------- workspace layout (float words, 16B-aligned blocks) ----------------
    float* ws    = (float*)d_ws;
    int*   modes = (int*)ws;                        // 64
    float* stats = ws + 64;                         // 1024 (sc/sh only)
    float* dinv  = ws + 1088;                       // 51200
    float* xsg   = ws + 52288;                      // 6400
    int*   bsum  = (int*)(ws + 58688);              // 256
    int*   rp_n  = (int*)(ws + 58944);              // 100001
    int*   adj_n = (int*)(ws + 158948);             // 800000
    int*   rp_s  = (int*)(ws + 958948);             // 51201
    int*   adj_s = (int*)(ws + 1010152);            // 409600
    short* adw_s = (short*)(ws + 1419752);          // 409600 shorts
    short* wtb   = (short*)(ws + 1624552);          // 262144 shorts
    float* xg    = ws + 1755624;                    // 131072 (also cur_n early)
    float* part  = ws + 1886696;                    // 51200  (also cur_s early)
    float* A25   = ws + 1937896;                    // 25,600,000 (only ~13.11M used)
    float* B13   = ws + 27537896;                   // 13,107,200
    float* C13   = ws + 40645096;                   // 13,107,200
    size_t need  = (size_t)53752296 * 4;
    if (ws_size < need) return;
    int* cur_n = (int*)xg;
    int* cur_s = (int*)part;
    int* bsum_n = bsum;
    int* bsum_s = bsum + 128;
    // replicated stats buffer in A25's dead tail (A25 usage peaks at 13,107,200 floats)
    float* statsR = A25 + 13200000;                 // NREP*512 = 8192 floats

    unsigned short* A25B = (unsigned short*)A25;
    unsigned short* B13B = (unsigned short*)B13;
    unsigned short* C13B = (unsigned short*)C13;
    float* B13F = B13;  float* A25F = A25;

    // BN sc/sh locations inside stats: C=256 -> sc@512, sh@768 ; C=128 -> sc@256, sh@384
    float* sc256 = stats + 512; float* sh256 = stats + 768;
    float* sc128 = stats + 256; float* sh128 = stats + 384;

    short* wt0 = wtb;               // g0_W1  256 x 96
    short* wt1 = wt0 + 24576;       // g0_W2  128 x 256
    short* wt2 = wt1 + 32768;       // g1_W1  256 x 128
    short* wt3 = wt2 + 32768;       // g1_W2  128 x 256
    short* wt4 = wt3 + 32768;       // nl_W   128 x 128
    short* wt5 = wt4 + 16384;       // c0_W   256 x 96
    short* wt6 = wt5 + 24576;       // c1_W   256 x 256
    short* wt7 = wt6 + 65536;       // sl_W   128 x 256

    // ---------------- detect dtypes (once, 35 blocks) ----------------
    static const int conv_idx[NCONV] = {1, 4, 6, 10, 11,
        12, 13, 14, 15, 16, 17, 18, 19, 20,
        21, 22, 23, 24, 25, 26, 27, 28, 29,
        30, 31, 32, 33, 34, 35, 36, 37, 38, 39, 40, 41};
    DetArgs da;
    for (int b = 0; b < NCONV; ++b) { da.src[b] = d_in[conv_idx[b]]; da.n[b] = in_sizes[conv_idx[b]]; }
    detect_all<<<NCONV, 256, 0, stream>>>(da, modes);

    // ---------------- weight transposes (batched) ----------------
    {
        WtArgs wa;
        const int din_i[8]  = {12, 16, 21, 25, 30, 32, 36, 40};
        const int midx_i[8] = {5, 9, 14, 18, 23, 25, 29, 33};
        const int KW_i[8]   = {70, 256, 128, 256, 128, 68, 256, 256};
        const int ldw_i[8]  = {256, 128, 256, 128, 128, 256, 256, 128};
        short* wt_i[8]      = {wt0, wt1, wt2, wt3, wt4, wt5, wt6, wt7};
        const int Kp_i[8]   = {96, 256, 128, 256, 128, 96, 256, 256};
        const int N_i[8]    = {256, 128, 256, 128, 128, 256, 256, 128};
        for (int e = 0; e < 8; ++e) {
            wa.W[e] = d_in[din_i[e]]; wa.midx[e] = midx_i[e]; wa.KW[e] = KW_i[e];
            wa.ldw[e] = ldw_i[e]; wa.wt[e] = wt_i[e]; wa.Kpad[e] = Kp_i[e]; wa.N[e] = N_i[e];
        }
        wt_build_all<<<dim3(256, 8), 256, 0, stream>>>(wa, modes);
    }

    // ---------------- degrees (before CSR fill so adjw can fold dinv) ----------------
    hipMemsetAsync(dinv, 0, nS * sizeof(float), stream);
    deg_scatter<<<(nES + 255) / 256, 256, 0, stream>>>(d_in[6], modes, 2, eis + nES, dinv, nES);
    dinv_fin<<<(nS + 255) / 256, 256, 0, stream>>>(dinv, nS);

    // ---------------- CSR builds (hierarchical scan) ----------------
    const int nbN = (nN + 1023) / 1024, nbS = (nS + 1023) / 1024;
    hipMemsetAsync(cur_n, 0, nN * sizeof(int), stream);
    csr_count<<<(nE + 255) / 256, 256, 0, stream>>>(ei + nE, nE, cur_n);
    scan_part<<<nbN, 256, 0, stream>>>(cur_n, nN, bsum_n);
    scan_mid<<<1, 128, 0, stream>>>(bsum_n, nbN, rp_n, nN);
    scan_fin<<<nbN, 256, 0, stream>>>(cur_n, nN, bsum_n, rp_n, cur_n);
    csr_fill<<<(nE + 255) / 256, 256, 0, stream>>>(ei, ei + nE, nullptr, modes, 2, nullptr,
                                                   nE, cur_n, adj_n, nullptr);

    hipMemsetAsync(cur_s, 0, nS * sizeof(int), stream);
    csr_count<<<(nES + 255) / 256, 256, 0, stream>>>(eis + nES, nES, cur_s);
    scan_part<<<nbS, 256, 0, stream>>>(cur_s, nS, bsum_s);
    scan_mid<<<1, 128, 0, stream>>>(bsum_s, nbS, rp_s, nS);
    scan_fin<<<nbS, 256, 0, stream>>>(cur_s, nS, bsum_s, rp_s, cur_s);
    csr_fill<<<(nES + 255) / 256, 256, 0, stream>>>(eis, eis + nES, d_in[6], modes, 2, dinv,
                                                    nES, cur_s, adj_s, adw_s);

    auto gemm = [&](const void* A, int afmt, int ldk, const float* bsc, const float* bsh,
                    const short* Wt, const void* bias, int bidx,
                    float* outF, unsigned short* oB, int M, int N, int om) {
        if (om == 1) hipMemsetAsync(statsR, 0, NREP * 512 * sizeof(float), stream);
        dim3 grid(N / 128, (M + 127) / 128);
        gemm_mfma<<<grid, 256, 0, stream>>>(A, afmt, ldk, bsc, bsh, Wt, bias, modes, bidx,
                                            outF, oB, statsR, M, N, ldk / 32, om);
    };
    auto bnfin = [&](int gidx, int bidx, const void* g, const void* b, int C, int M) {
        bn_finalize<<<1, C, 0, stream>>>(statsR, stats, g, b, modes, gidx, bidx, C, 1.0f / M);
    };

    // ---------------- node branch ----------------
    build_feat_bf16<<<nN, 128, 0, stream>>>(d_in[10], node_ids, d_in[1], modes, 3, 0,
                                            C13B, 6, 96);
    gin_gather_bf16<<<(nN + 15) / 16, 256, 0, stream>>>(C13B, rp_n, adj_n, d_in[18], modes, 11,
                                                        nullptr, nullptr, B13B, 96, nN);
    gemm(B13B, 0, 96, nullptr, nullptr, wt0, d_in[13], 6, nullptr, A25B, nN, 256, 1);
    bnfin(7, 8, d_in[14], d_in[15], 256, nN);                       // BN1 -> sc256/sh256
    gemm(A25B, 0, 256, sc256, sh256, wt1, d_in[17], 10, nullptr, C13B, nN, 128, 1);
    bnfin(12, 13, d_in[19], d_in[20], 128, nN);                     // BN2 -> sc128/sh128
    gin_gather_bf16<<<(nN + 15) / 16, 256, 0, stream>>>(C13B, rp_n, adj_n, d_in[27], modes, 20,
                                                        sc128, sh128, B13B, 128, nN);
    gemm(B13B, 0, 128, nullptr, nullptr, wt2, d_in[22], 15, nullptr, A25B, nN, 256, 1);
    bnfin(16, 17, d_in[23], d_in[24], 256, nN);                     // BN3
    gemm(A25B, 0, 256, sc256, sh256, wt3, d_in[26], 19, nullptr, C13B, nN, 128, 1);
    bnfin(21, 22, d_in[28], d_in[29], 128, nN);                     // BN4
    gemm(C13B, 0, 128, sc128, sh128, wt4, d_in[31], 24, nullptr, B13B, nN, 128, 2);
    pool_sorted_bf16<<<Bg, 128, 0, stream>>>(B13B, batch, xg, nN);

    // ---------------- service branch ----------------
    build_feat_bf16<<<nS, 128, 0, stream>>>(d_in[11], svc_ids, d_in[4], modes, 4, 1,
                                            C13B, 4, 96);
    gemm(C13B, 0, 96, nullptr, nullptr, wt5, nullptr, 0, nullptr, B13B, nS, 256, 2);
    gcn_gather_bf16<<<(nS + 7) / 8, 256, 0, stream>>>(B13B, rp_s, adj_s, adw_s, dinv, d_in[33],
                                                      modes, 26, A25F, nS);
    hipMemsetAsync(statsR, 0, NREP * 512 * sizeof(float), stream);
    bn_stats_f32<<<(nS + 31) / 32, 256, 0, stream>>>(A25F, statsR, nS, 256, 32);
    bnfin(27, 28, d_in[34], d_in[35], 256, nS);
    gemm(A25F, 1, 256, sc256, sh256, wt6, nullptr, 0, nullptr, B13B, nS, 256, 2);
    gcn_gather_bf16<<<(nS + 7) / 8, 256, 0, stream>>>(B13B, rp_s, adj_s, adw_s, dinv, d_in[37],
                                                      modes, 30, A25F, nS);
    hipMemsetAsync(statsR, 0, NREP * 512 * sizeof(float), stream);
    bn_stats_f32<<<(nS + 31) / 32, 256, 0, stream>>>(A25F, statsR, nS, 256, 32);
    bnfin(31, 32, d_in[38], d_in[39], 256, nS);
    gemm(A25F, 1, 256, sc256, sh256, wt7, d_in[41], 34, B13F, nullptr, nS, 128, 0);
    svc_pool1<<<dim3(50, 8), 128, 0, stream>>>(B13F, part);
    svc_pool2<<<50, 128, 0, stream>>>(part, xsg);

    // ---------------- output ----------------
    final_out<<<Bg, 64, 0, stream>>>(xg, xsg, modes, d_out);
}